// Round 12
// baseline (213.591 us; speedup 1.0000x reference)
//
#include <hip/hip_runtime.h>

typedef _Float16 h2 __attribute__((ext_vector_type(2)));
typedef _Float16 h4 __attribute__((ext_vector_type(4)));
typedef _Float16 h8 __attribute__((ext_vector_type(8)));
typedef float f4 __attribute__((ext_vector_type(4)));
typedef unsigned int u32;
typedef u32 u32x2 __attribute__((ext_vector_type(2)));
typedef u32 u32x4 __attribute__((ext_vector_type(4)));

__device__ __forceinline__ h2 bch2(u32 v) { return __builtin_bit_cast(h2, v); }

__device__ __forceinline__ float warpsum(float v) {
    for (int off = 32; off > 0; off >>= 1) v += __shfl_down(v, off);
    return v;
}

// swizzle (stride 64): XOR k-block with p-row-group; keeps 8-elem (16B) blocks contiguous
__device__ __forceinline__ int sswz(int p, int k) {
    return p * 64 + ((((k >> 3) ^ (p >> 3)) & 7) << 3) + (k & 7);
}

// ---------------- K_prep: hwH [144][72] fp16 k-padded; lwC [64][64] combined; bias_comb f32[64] ----------------
__global__ __launch_bounds__(256) void k_prep(const float* __restrict__ hid_w,
                                              const float* __restrict__ out_w,
                                              const float* __restrict__ last_w,
                                              const float* __restrict__ out_b,
                                              const float* __restrict__ last_b,
                                              _Float16* __restrict__ hwH,
                                              _Float16* __restrict__ lwC,
                                              float* __restrict__ bias_comb) {
    int t = blockIdx.x * 256 + threadIdx.x;
    int stride = gridDim.x * 256;
    for (int i = t; i < 10368; i += stride) {           // 144*72
        int n = i / 72, k = i - n * 72;
        hwH[i] = (k < 48) ? (_Float16)hid_w[n * 48 + k] : (_Float16)0.f;
    }
    for (int i = t; i < 4096; i += stride) {            // 64*64
        int n = i >> 6, k = i & 63;
        float v;
        if (k < 16) v = last_w[n * 64 + k];
        else {
            v = 0.f;
            for (int o = 0; o < 48; ++o) v += last_w[n * 64 + 16 + o] * out_w[o * 48 + (k - 16)];
        }
        lwC[i] = (_Float16)v;
    }
    for (int n = t; n < 64; n += stride) {
        float v = last_b[n];
        for (int o = 0; o < 48; ++o) v += last_w[n * 64 + 16 + o] * out_b[o];
        bias_comb[n] = v;
    }
}

// ---------------- K0: pooled mean of x1 channels ----------------
__global__ __launch_bounds__(256) void k_pool(const float* __restrict__ x, float* __restrict__ pooled1) {
    int bid = blockIdx.x;            // 64 = b*16 + c
    int b = bid >> 4, c = bid & 15;
    const float* base = x + (size_t)(b * 64 + c) * 65536;
    float s = 0.f;
    for (int i = threadIdx.x; i < 16384; i += 256) {
        float4 v = ((const float4*)base)[i];
        s += v.x + v.y + v.z + v.w;
    }
    __shared__ float red[4];
    s = warpsum(s);
    if ((threadIdx.x & 63) == 0) red[threadIdx.x >> 6] = s;
    __syncthreads();
    if (threadIdx.x == 0) pooled1[bid] = (red[0] + red[1] + red[2] + red[3]) * (1.f / 65536.f);
}

// ---------------- K1: kern1 from pooled1 (tiny MLP) ----------------
__global__ __launch_bounds__(256) void k_kern1(const float* __restrict__ pooled1,
                                               const float* __restrict__ w1, const float* __restrict__ b1,
                                               const float* __restrict__ w2, const float* __restrict__ b2,
                                               float* __restrict__ kern1) {
    __shared__ float h[64];
    int t = threadIdx.x;
    if (t < 64) {
        int b = t >> 4, j = t & 15;
        float a = b1[j];
        for (int i = 0; i < 16; ++i) a += pooled1[b * 16 + i] * w1[j * 16 + i];
        h[t] = fmaxf(a, 0.f);
    }
    __syncthreads();
    for (int i = t; i < 576; i += 256) {      // 4 * 144
        int b = i / 144, o = i - b * 144;
        float a = b2[o];
        for (int j = 0; j < 16; ++j) a += h[b * 16 + j] * w2[o * 16 + j];
        kern1[i] = a;
    }
}

// ---------------- K2: dynamic depthwise 3x3 (8 rows/block, LDS-staged) + row sums ----------------
__global__ __launch_bounds__(256) void k_dw3(const float* __restrict__ x,
                                             const float* __restrict__ kern1,
                                             float* __restrict__ y1, float* __restrict__ rowsum) {
    __shared__ float tile[10][258];
    __shared__ float red[8][4];
    int bid = blockIdx.x;            // bc*32 + rb
    int rb = bid & 31, bc = bid >> 5;
    int b = bc >> 4, c = bc & 15;
    int row0 = rb << 3;
    int col = threadIdx.x;
    const float* xc = x + ((size_t)(b * 64 + c) << 16);
#pragma unroll
    for (int j = 0; j < 10; ++j) {
        int r = row0 - 1 + j;
        tile[j][col + 1] = ((unsigned)r < 256u) ? xc[(r << 8) + col] : 0.f;
    }
    if (col < 10) { tile[col][0] = 0.f; tile[col][257] = 0.f; }
    const float* k9 = kern1 + b * 144 + c * 9;
    float kk[9];
#pragma unroll
    for (int i = 0; i < 9; ++i) kk[i] = k9[i];
    __syncthreads();
#pragma unroll
    for (int j = 0; j < 8; ++j) {
        float acc = 0.f;
#pragma unroll
        for (int dy = 0; dy < 3; ++dy)
#pragma unroll
            for (int dx = 0; dx < 3; ++dx)
                acc += kk[dy * 3 + dx] * tile[j + dy][col + dx];
        y1[((size_t)bc << 16) + ((row0 + j) << 8) + col] = acc;
        float s = warpsum(acc);
        if ((col & 63) == 0) red[j][col >> 6] = s;
    }
    __syncthreads();
    if (col < 8) rowsum[bc * 256 + row0 + col] = red[col][0] + red[col][1] + red[col][2] + red[col][3];
}

// ---------------- K3: kern2 from row sums (tiny MLP) ----------------
__global__ __launch_bounds__(256) void k_kern2(const float* __restrict__ rowsum,
                                               const float* __restrict__ w1, const float* __restrict__ b1,
                                               const float* __restrict__ w2, const float* __restrict__ b2,
                                               float* __restrict__ kern2) {
    __shared__ float ps[256];
    __shared__ float p2[64];
    __shared__ float h[64];
    int t = threadIdx.x;
    {
        int pair = t >> 2, seg = t & 3;
        const float* rs = rowsum + pair * 256 + seg * 64;
        float s = 0.f;
        for (int j = 0; j < 64; ++j) s += rs[j];
        ps[t] = s;
    }
    __syncthreads();
    if (t < 64) p2[t] = (ps[t * 4] + ps[t * 4 + 1] + ps[t * 4 + 2] + ps[t * 4 + 3]) * (1.f / 65536.f);
    __syncthreads();
    if (t < 64) {
        int b = t >> 4, j = t & 15;
        float a = b1[j];
        for (int i = 0; i < 16; ++i) a += p2[b * 16 + i] * w1[j * 16 + i];
        h[t] = fmaxf(a, 0.f);
    }
    __syncthreads();
    for (int i = t; i < 1600; i += 256) {     // 4 * 400
        int b = i / 400, o = i - b * 400;
        float a = b2[o];
        for (int j = 0; j < 16; ++j) a += h[b * 16 + j] * w2[o * 16 + j];
        kern2[i] = a;
    }
}

// ---------------- K4: dynamic depthwise 5x5 (8 rows/block, LDS-staged) ----------------
__global__ __launch_bounds__(256) void k_dw5(const float* __restrict__ y1,
                                             const float* __restrict__ kern2,
                                             float* __restrict__ x1o) {
    __shared__ float tile[12][260];
    int bid = blockIdx.x;            // bc*32 + rb
    int rb = bid & 31, bc = bid >> 5;
    int b = bc >> 4, c = bc & 15;
    int row0 = rb << 3;
    int col = threadIdx.x;
    const float* yc = y1 + ((size_t)bc << 16);
#pragma unroll
    for (int j = 0; j < 12; ++j) {
        int r = row0 - 2 + j;
        tile[j][col + 2] = ((unsigned)r < 256u) ? yc[(r << 8) + col] : 0.f;
    }
    if (col < 12) { tile[col][0] = 0.f; tile[col][1] = 0.f; tile[col][258] = 0.f; tile[col][259] = 0.f; }
    const float* k25 = kern2 + b * 400 + c * 25;
    float kk[25];
#pragma unroll
    for (int i = 0; i < 25; ++i) kk[i] = k25[i];
    __syncthreads();
#pragma unroll
    for (int j = 0; j < 8; ++j) {
        float acc = 0.f;
#pragma unroll
        for (int dy = 0; dy < 5; ++dy)
#pragma unroll
            for (int dx = 0; dx < 5; ++dx)
                acc += kk[dy * 5 + dx] * tile[j + dy][col + dx];
        x1o[((size_t)bc << 16) + ((row0 + j) << 8) + col] = acc;
    }
}

// ---------------- K5: fused fsas + final conv, channel-major hidden GEMM, 5 barriers ----------------
// LDS 52.3 KB -> 3 blocks/CU:
//   Abuf [128][72] f16 (18.0KB): x2 halo (B-operand, px-major). Overlay after B2: fbuf [64][64] sswz.
//   hbuf [144][120] f16 (33.8KB): hidden halo, CHANNEL-major rows. dw output (q/krev/v) overwrites
//     own row's cols 0..63 (each wave owns its 16 channels' rows -> MFMA->dw is wave-local, NO barrier).
//   lnp f32[128] (LN sum/sumsq per px, ds_add_f32 atomics) -> mu/inv in place.
// Wave w: M-tile w (ch 16w..16w+15) + N-tile w of M-tile 8 (ch 128-143, split across waves).
// Tile-8 dw runs on conv-idle lanes 48-63 of every wave. Final GEMM uses lwC fold.
__global__ __launch_bounds__(512, 6) void k_fsas(const float* __restrict__ x,
                                                 const _Float16* __restrict__ hwH, const float* __restrict__ hid_b,
                                                 const float* __restrict__ dw_w, const float* __restrict__ dw_b,
                                                 const float* __restrict__ ln_w, const float* __restrict__ ln_b,
                                                 const _Float16* __restrict__ lwC, const float* __restrict__ bias_comb,
                                                 const float* __restrict__ x1o, float* __restrict__ out) {
    __shared__ __align__(16) _Float16 Abuf[9216];    // [128][72]
    __shared__ __align__(16) _Float16 hbuf[17280];   // [144][120]
    __shared__ __align__(16) float lnp[128];

    _Float16* fbuf = Abuf;                           // [64][64] sswz overlay (valid after B2)

    int tid = threadIdx.x;
    int lane = tid & 63;
    int wave = __builtin_amdgcn_readfirstlane(tid >> 6);
    int bid = blockIdx.x;
    int swz = ((bid & 7) << 9) | (bid >> 3);         // bijective XCD swizzle (4096 = 8*512)
    int b = swz >> 10;
    int rem = swz & 1023;
    int row0 = (rem >> 5) << 3, col0 = (rem & 31) << 3;

    int l16 = lane & 15, lhi = lane >> 4;

    // ---- x1o early loads for waves 6-7 (written to fbuf at sbuf stage) ----
    float xr[8];
    int fgrp = wave - 6;
    if (wave >= 6) {
        size_t gp = ((size_t)(row0 + (lane >> 3)) << 8) + col0 + (lane & 7);
#pragma unroll
        for (int j = 0; j < 8; ++j)
            xr[j] = x1o[((size_t)(b * 16 + fgrp * 8 + j) << 16) + gp];
    }

    // ---- stage 1: fill A halo (p = y*12+x, k-pairs) + zero k-pad + zero lnp ----
    if (tid < 480) {
        int k2 = tid / 20, r20 = tid - (tid / 20) * 20;
        int y = r20 >> 1, xh = r20 & 1;
        int gy = row0 - 1 + y;
        bool rowok = (unsigned)gy < 256u;
        const float* xa = x + ((size_t)(b * 64 + 16 + 2 * k2) << 16) + ((size_t)(gy & 255) << 8);
        const float* xb = xa + 65536;
#pragma unroll
        for (int xx = 0; xx < 6; ++xx) {
            int xv = xh * 6 + xx;
            int gx = col0 - 1 + xv;
            bool ok = rowok && (xv < 10) && ((unsigned)gx < 256u);
            float va = ok ? xa[gx] : 0.f;
            float vb = ok ? xb[gx] : 0.f;
            *(h2*)(Abuf + (y * 12 + xv) * 72 + 2 * k2) = (h2){(_Float16)va, (_Float16)vb};
        }
    }
    if (tid < 256) {                    // k 48..63, rows 0..127 (zero so 0-weight pads can't make NaN)
        int p = tid >> 1, kb = 48 + ((tid & 1) << 3);
        *(h8*)(Abuf + p * 72 + kb) = (h8)(_Float16)0.f;
    }
    if (tid < 128) lnp[tid] = 0.f;
    __syncthreads();                    // B1

    // ---- stage 2: hidden GEMM channel-major; wave-local output rows ----
    const _Float16* wrO = hwH + (wave * 16 + l16) * 72 + (lhi << 3);
    h8 wa0 = *(const h8*)(wrO);
    h8 wa1 = *(const h8*)(wrO + 32);
    const _Float16* wr8 = hwH + (128 + l16) * 72 + (lhi << 3);
    h8 w80 = *(const h8*)(wr8);
    h8 w81 = *(const h8*)(wr8 + 32);
    f4 biasO = *(const f4*)(hid_b + wave * 16 + (lhi << 2));
    f4 bias8 = *(const f4*)(hid_b + 128 + (lhi << 2));
    int chbO = wave * 16 + (lhi << 2);
    h8 xbs0, xbs1;
#pragma unroll
    for (int nt = 0; nt < 8; ++nt) {
        int px = nt * 16 + l16;
        h8 xb0 = *(const h8*)(Abuf + px * 72 + (lhi << 3));
        h8 xb1 = *(const h8*)(Abuf + px * 72 + 32 + (lhi << 3));
        if (nt == wave) { xbs0 = xb0; xbs1 = xb1; }
        f4 acc = biasO;
        acc = __builtin_amdgcn_mfma_f32_16x16x32_f16(wa0, xb0, acc, 0, 0, 0);
        acc = __builtin_amdgcn_mfma_f32_16x16x32_f16(wa1, xb1, acc, 0, 0, 0);
        if (px < 120) {
            int yv = px / 12, xv = px - yv * 12;
            bool ok = (xv < 10) && ((unsigned)(row0 - 1 + yv) < 256u) && ((unsigned)(col0 - 1 + xv) < 256u);
#pragma unroll
            for (int r = 0; r < 4; ++r)
                hbuf[(chbO + r) * 120 + px] = ok ? (_Float16)acc[r] : (_Float16)0.f;
        }
    }
    {   // M-tile 8 (v channels 128-143), N-tile = wave
        int px = wave * 16 + l16;
        f4 acc = bias8;
        acc = __builtin_amdgcn_mfma_f32_16x16x32_f16(w80, xbs0, acc, 0, 0, 0);
        acc = __builtin_amdgcn_mfma_f32_16x16x32_f16(w81, xbs1, acc, 0, 0, 0);
        if (px < 120) {
            int yv = px / 12, xv = px - yv * 12;
            bool ok = (xv < 10) && ((unsigned)(row0 - 1 + yv) < 256u) && ((unsigned)(col0 - 1 + xv) < 256u);
#pragma unroll
            for (int r = 0; r < 4; ++r)
                hbuf[(128 + (lhi << 2) + r) * 120 + px] = ok ? (_Float16)acc[r] : (_Float16)0.f;
        }
    }

    // ---- stage 3 (NO barrier): depthwise 3x3 on own 16 channels, via fdot2 ----
    auto dw_row = [&](int ch, int row, float o[8]) {
        const float* dwp = dw_w + ch * 9;
        float bias = dw_b[ch];
#pragma unroll
        for (int xx = 0; xx < 8; ++xx) o[xx] = bias;
        const _Float16* hb = hbuf + ch * 120 + row * 12;
#pragma unroll
        for (int dy = 0; dy < 3; ++dy) {
            u32x2 A2 = *(const u32x2*)(hb + dy * 12);
            u32x2 B2 = *(const u32x2*)(hb + dy * 12 + 4);
            u32 r89 = *(const u32*)(hb + dy * 12 + 8);
            u32 r01 = A2.x, r23 = A2.y, r45 = B2.x, r67 = B2.y;
            u32 s12 = __builtin_amdgcn_alignbit(r23, r01, 16);
            u32 s34 = __builtin_amdgcn_alignbit(r45, r23, 16);
            u32 s56 = __builtin_amdgcn_alignbit(r67, r45, 16);
            u32 s78 = __builtin_amdgcn_alignbit(r89, r67, 16);
            _Float16 w0 = (_Float16)dwp[dy * 3], w1 = (_Float16)dwp[dy * 3 + 1], w2 = (_Float16)dwp[dy * 3 + 2];
            h2 w01 = {w0, w1};
            h2 w2lo = {w2, (_Float16)0.f};
            h2 w2hi = {(_Float16)0.f, w2};
            o[0] = __builtin_amdgcn_fdot2(w01, bch2(r01), o[0], false);
            o[0] = __builtin_amdgcn_fdot2(w2lo, bch2(r23), o[0], false);
            o[1] = __builtin_amdgcn_fdot2(w01, bch2(s12), o[1], false);
            o[1] = __builtin_amdgcn_fdot2(w2lo, bch2(s34), o[1], false);
            o[2] = __builtin_amdgcn_fdot2(w01, bch2(r23), o[2], false);
            o[2] = __builtin_amdgcn_fdot2(w2lo, bch2(r45), o[2], false);
            o[3] = __builtin_amdgcn_fdot2(w01, bch2(s34), o[3], false);
            o[3] = __builtin_amdgcn_fdot2(w2lo, bch2(s56), o[3], false);
            o[4] = __builtin_amdgcn_fdot2(w01, bch2(r45), o[4], false);
            o[4] = __builtin_amdgcn_fdot2(w2lo, bch2(r67), o[4], false);
            o[5] = __builtin_amdgcn_fdot2(w01, bch2(s56), o[5], false);
            o[5] = __builtin_amdgcn_fdot2(w2lo, bch2(s78), o[5], false);
            o[6] = __builtin_amdgcn_fdot2(w01, bch2(r67), o[6], false);
            o[6] = __builtin_amdgcn_fdot2(w2lo, bch2(r89), o[6], false);
            o[7] = __builtin_amdgcn_fdot2(w01, bch2(s78), o[7], false);
            o[7] = __builtin_amdgcn_fdot2(w2hi, bch2(r89), o[7], false);
        }
    };
    auto route_write = [&](int c, int m, float o[8]) {
        h8 v8;
        if (c >= 48 && c < 96) {
#pragma unroll
            for (int t2 = 0; t2 < 8; ++t2) v8[t2] = (_Float16)o[(8 - t2) & 7];   // krev
        } else {
#pragma unroll
            for (int t2 = 0; t2 < 8; ++t2) v8[t2] = (_Float16)o[t2];             // q / v plain
        }
        *(h8*)(hbuf + c * 120 + m * 8) = v8;
    };
    {
        int c1 = wave * 16 + (lane >> 3), m1 = lane & 7;           // tasks 0..127 of own tile
        int c2 = wave * 16 + 8 + (lane >> 3), m2 = lane & 7;       // (lane+64)>>3 = 8 + lane>>3
        float o1[8], o2[8];
        dw_row(c1, m1, o1);
        dw_row(c2, m2, o2);
        route_write(c1, m1, o1);       // all reads precede writes (wave lockstep)
        route_write(c2, m2, o2);
    }
    __syncthreads();                    // B2

    // ---- stage 4: circular conv (lanes 0-47) / tile-8 dw (lanes 48-63) ----
    float co[8];
    int cch = wave * 6 + (lane >> 3);   // conv channel (lanes<48)
    int cm = lane & 7;
    if (lane < 48) {
#pragma unroll
        for (int n = 0; n < 8; ++n) co[n] = 0.f;
#pragma unroll
        for (int i8 = 0; i8 < 8; ++i8) {
            int r = (cm - i8) & 7;
            u32x4 qv = *(const u32x4*)(hbuf + cch * 120 + i8 * 8);
            u32x4 ev = *(const u32x4*)(hbuf + (48 + cch) * 120 + r * 8);
            h2 qp[4] = {bch2(qv.x), bch2(qv.y), bch2(qv.z), bch2(qv.w)};
            h2 ep[4] = {bch2(ev.x), bch2(ev.y), bch2(ev.z), bch2(ev.w)};
            h2 op[4] = {bch2(__builtin_amdgcn_alignbit(ev.x, ev.w, 16)),
                        bch2(__builtin_amdgcn_alignbit(ev.y, ev.x, 16)),
                        bch2(__builtin_amdgcn_alignbit(ev.z, ev.y, 16)),
                        bch2(__builtin_amdgcn_alignbit(ev.w, ev.z, 16))};
#pragma unroll
            for (int u = 0; u < 4; ++u)
#pragma unroll
                for (int a = 0; a < 4; ++a) {
                    co[2 * u]     = __builtin_amdgcn_fdot2(qp[a], ep[(a - u) & 3], co[2 * u], false);
                    co[2 * u + 1] = __builtin_amdgcn_fdot2(qp[a], op[(a - u) & 3], co[2 * u + 1], false);
                }
        }
    } else {
        int c8 = 128 + wave * 2 + ((lane >> 3) & 1);   // 2 tile-8 channels per wave
        int m8 = lane & 7;
        float o8v[8];
        dw_row(c8, m8, o8v);
        h8 v8;
#pragma unroll
        for (int t2 = 0; t2 < 8; ++t2) v8[t2] = (_Float16)o8v[t2];
        *(h8*)(hbuf + c8 * 120 + m8 * 8) = v8;
#pragma unroll
        for (int n = 0; n < 8; ++n) co[n] = 0.f;
    }
    // wave-level LN partials: sum over the wave's 6 conv channels per pixel
    {
        float s[8], ss[8];
#pragma unroll
        for (int n = 0; n < 8; ++n) { s[n] = co[n]; ss[n] = co[n] * co[n]; }
#pragma unroll
        for (int off = 8; off < 64; off <<= 1) {
#pragma unroll
            for (int n = 0; n < 8; ++n) {
                s[n] += __shfl_xor(s[n], off);
                ss[n] += __shfl_xor(ss[n], off);
            }
        }
        if (lane < 8) {
#pragma unroll
            for (int n = 0; n < 8; ++n) {
                atomicAdd(&lnp[(lane * 8 + n) * 2], s[n]);
                atomicAdd(&lnp[(lane * 8 + n) * 2 + 1], ss[n]);
            }
        }
    }
    __syncthreads();                    // B3

    if (tid < 64) {
        float sv = lnp[tid * 2], ssv = lnp[tid * 2 + 1];
        float mu = sv * (1.f / 48.f);
        float var = ssv * (1.f / 48.f) - mu * mu;
        lnp[tid * 2] = mu;
        lnp[tid * 2 + 1] = rsqrtf(var + 1e-6f);
    }
    __syncthreads();                    // B4

    // ---- stage 5: fbuf = [x1 | v*layernorm(conv)] (sswz) ----
    if (lane < 48) {
        float lw = ln_w[cch], lb = ln_b[cch];
        h8 vv = *(const h8*)(hbuf + (96 + cch) * 120 + cm * 8);
#pragma unroll
        for (int n = 0; n < 8; ++n) {
            int p = cm * 8 + n;
            float mu = lnp[p * 2], inv = lnp[p * 2 + 1];
            float lnv = lw * ((co[n] - mu) * inv) + lb;
            fbuf[sswz(p, 16 + cch)] = (_Float16)((float)vv[n] * lnv);
        }
    }
    if (wave >= 6) {
        h8 fv;
#pragma unroll
        for (int j = 0; j < 8; ++j) fv[j] = (_Float16)xr[j];
        *(h8*)(fbuf + sswz(lane, fgrp * 8)) = fv;
    }
    __syncthreads();                    // B5

    // ---- stage 6: out = lwC @ [x1;sbuf] + bias_comb (K=64 MFMA) -> direct global float4 ----
    for (int t = wave; t < 16; t += 8) {
        int mt = t >> 2, nt = t & 3;
        int row6 = mt * 16 + l16;
        h8 c0 = *(const h8*)(fbuf + sswz(row6, lhi << 3));
        h8 c1 = *(const h8*)(fbuf + sswz(row6, 32 + (lhi << 3)));
        h8 d0 = *(const h8*)(lwC + (nt * 16 + l16) * 64 + (lhi << 3));
        h8 d1 = *(const h8*)(lwC + (nt * 16 + l16) * 64 + 32 + (lhi << 3));
        float bias = bias_comb[nt * 16 + l16];
        f4 acc = {bias, bias, bias, bias};
        acc = __builtin_amdgcn_mfma_f32_16x16x32_f16(c0, d0, acc, 0, 0, 0);
        acc = __builtin_amdgcn_mfma_f32_16x16x32_f16(c1, d1, acc, 0, 0, 0);
        int ch = nt * 16 + l16;
        int px0 = mt * 16 + (lhi << 2);
        float4 val = {acc[0], acc[1], acc[2], acc[3]};
        *(float4*)(out + ((size_t)(b * 64 + ch) << 16) + ((size_t)(row0 + (px0 >> 3)) << 8) + col0 + (px0 & 7)) = val;
    }
}

extern "C" void kernel_launch(void* const* d_in, const int* in_sizes, int n_in,
                              void* d_out, int out_size, void* d_ws, size_t ws_size,
                              hipStream_t stream) {
    const float* x      = (const float*)d_in[0];
    const float* dl1_w1 = (const float*)d_in[1];
    const float* dl1_b1 = (const float*)d_in[2];
    const float* dl1_w2 = (const float*)d_in[3];
    const float* dl1_b2 = (const float*)d_in[4];
    const float* dl2_w1 = (const float*)d_in[5];
    const float* dl2_b1 = (const float*)d_in[6];
    const float* dl2_w2 = (const float*)d_in[7];
    const float* dl2_b2 = (const float*)d_in[8];
    const float* hid_w  = (const float*)d_in[9];
    const float* hid_b  = (const float*)d_in[10];
    const float* dw_w   = (const float*)d_in[11];
    const float* dw_b   = (const float*)d_in[12];
    const float* ln_w   = (const float*)d_in[13];
    const float* ln_b   = (const float*)d_in[14];
    const float* out_w  = (const float*)d_in[15];
    const float* out_b  = (const float*)d_in[16];
    const float* last_w = (const float*)d_in[17];
    const float* last_b = (const float*)d_in[18];
    float* out = (float*)d_out;

    float* ws      = (float*)d_ws;
    float* pooled1 = ws;                       // 64
    float* kern1   = ws + 64;                  // 576
    float* rowsum  = ws + 1024;                // 16384
    float* kern2   = ws + 17408;               // 1600
    _Float16* hwH   = (_Float16*)(ws + 19008); // 10368 fp16 -> ends 24192
    _Float16* lwC   = (_Float16*)(ws + 24192); // 4096 fp16 -> ends 26240
    float* bias_comb = ws + 26240;             // 64 f32 -> ends 26304
    float* y1      = ws + 32768;               // 4194304
    float* x1o     = ws + 32768 + 4194304;     // 4194304

    k_prep <<<8,    256, 0, stream>>>(hid_w, out_w, last_w, out_b, last_b, hwH, lwC, bias_comb);
    k_pool <<<64,   256, 0, stream>>>(x, pooled1);
    k_kern1<<<1,    256, 0, stream>>>(pooled1, dl1_w1, dl1_b1, dl1_w2, dl1_b2, kern1);
    k_dw3  <<<2048, 256, 0, stream>>>(x, kern1, y1, rowsum);
    k_kern2<<<1,    256, 0, stream>>>(rowsum, dl2_w1, dl2_b1, dl2_w2, dl2_b2, kern2);
    k_dw5  <<<2048, 256, 0, stream>>>(y1, kern2, x1o);
    k_fsas <<<4096, 512, 0, stream>>>(x, hwH, hid_b, dw_w, dw_b, ln_w, ln_b,
                                      lwC, bias_comb, x1o, out);
}

// Round 13
// 165.726 us; speedup vs baseline: 1.2888x; 1.2888x over previous
//
#include <hip/hip_runtime.h>

typedef _Float16 h2 __attribute__((ext_vector_type(2)));
typedef _Float16 h4 __attribute__((ext_vector_type(4)));
typedef _Float16 h8 __attribute__((ext_vector_type(8)));
typedef float f4 __attribute__((ext_vector_type(4)));
typedef unsigned int u32;
typedef u32 u32x2 __attribute__((ext_vector_type(2)));
typedef u32 u32x4 __attribute__((ext_vector_type(4)));

__device__ __forceinline__ h2 bch2(u32 v) { return __builtin_bit_cast(h2, v); }

__device__ __forceinline__ float warpsum(float v) {
    for (int off = 32; off > 0; off >>= 1) v += __shfl_down(v, off);
    return v;
}

// swizzle for sbufA only: stride 64, XOR k-block with p>>3
__device__ __forceinline__ int sswz(int p, int k) {
    return p * 64 + ((((k >> 3) ^ (p >> 3)) & 7) << 3) + (k & 7);
}

// ---------------- K_preppool: fp16 weight matrices + pooled mean of x1 channels ----------------
// grid 64 x 256: block bid does pool for (b,c)=bid; weight prep strided across all threads.
__global__ __launch_bounds__(256) void k_preppool(const float* __restrict__ x,
                                                  const float* __restrict__ hid_w,
                                                  const float* __restrict__ out_w,
                                                  const float* __restrict__ last_w,
                                                  _Float16* __restrict__ hwH,
                                                  _Float16* __restrict__ owlwH,
                                                  float* __restrict__ pooled1) {
    int t = blockIdx.x * 256 + threadIdx.x;
    int stride = gridDim.x * 256;
    for (int i = t; i < 10368; i += stride) {           // 144*72
        int n = i / 72, k = i - n * 72;
        hwH[i] = (k < 48) ? (_Float16)hid_w[n * 48 + k] : (_Float16)0.f;
    }
    for (int i = t; i < 3456; i += stride) {            // 48*72
        int n = i / 72, k = i - n * 72;
        owlwH[i] = (k < 48) ? (_Float16)out_w[n * 48 + k] : (_Float16)0.f;
    }
    for (int i = t; i < 4608; i += stride) {            // 64*72
        int n = i / 72, k = i - n * 72;
        owlwH[3456 + i] = (k < 64) ? (_Float16)last_w[n * 64 + k] : (_Float16)0.f;
    }
    // pool: block bid handles (b,c) = bid
    int bid = blockIdx.x;
    int b = bid >> 4, c = bid & 15;
    const float* base = x + (size_t)(b * 64 + c) * 65536;
    float s = 0.f;
    for (int i = threadIdx.x; i < 16384; i += 256) {
        float4 v = ((const float4*)base)[i];
        s += v.x + v.y + v.z + v.w;
    }
    __shared__ float red[4];
    s = warpsum(s);
    if ((threadIdx.x & 63) == 0) red[threadIdx.x >> 6] = s;
    __syncthreads();
    if (threadIdx.x == 0) pooled1[bid] = (red[0] + red[1] + red[2] + red[3]) * (1.f / 65536.f);
}

// ---------------- K2: dynamic depthwise 3x3 with INLINE kern1 MLP + row sums ----------------
__global__ __launch_bounds__(256) void k_dw3(const float* __restrict__ x,
                                             const float* __restrict__ pooled1,
                                             const float* __restrict__ w1, const float* __restrict__ b1,
                                             const float* __restrict__ w2, const float* __restrict__ b2,
                                             float* __restrict__ y1, float* __restrict__ rowsum) {
    __shared__ float tile[10][258];
    __shared__ float red[8][4];
    __shared__ float kk9[9];
    int bid = blockIdx.x;            // bc*32 + rb
    int rb = bid & 31, bc = bid >> 5;
    int b = bc >> 4, c = bc & 15;
    int row0 = rb << 3;
    int col = threadIdx.x;
    // inline kern1: 9 threads each compute h[16] then one output tap
    if (col < 9) {
        float hloc[16];
#pragma unroll
        for (int j = 0; j < 16; ++j) {
            float a = b1[j];
#pragma unroll
            for (int i = 0; i < 16; ++i) a += pooled1[b * 16 + i] * w1[j * 16 + i];
            hloc[j] = fmaxf(a, 0.f);
        }
        int o = c * 9 + col;
        float a = b2[o];
#pragma unroll
        for (int j = 0; j < 16; ++j) a += hloc[j] * w2[o * 16 + j];
        kk9[col] = a;
    }
    const float* xc = x + ((size_t)(b * 64 + c) << 16);
#pragma unroll
    for (int j = 0; j < 10; ++j) {
        int r = row0 - 1 + j;
        tile[j][col + 1] = ((unsigned)r < 256u) ? xc[(r << 8) + col] : 0.f;
    }
    if (col < 10) { tile[col][0] = 0.f; tile[col][257] = 0.f; }
    __syncthreads();
    float kk[9];
#pragma unroll
    for (int i = 0; i < 9; ++i) kk[i] = kk9[i];
#pragma unroll
    for (int j = 0; j < 8; ++j) {
        float acc = 0.f;
#pragma unroll
        for (int dy = 0; dy < 3; ++dy)
#pragma unroll
            for (int dx = 0; dx < 3; ++dx)
                acc += kk[dy * 3 + dx] * tile[j + dy][col + dx];
        y1[((size_t)bc << 16) + ((row0 + j) << 8) + col] = acc;
        float s = warpsum(acc);
        if ((col & 63) == 0) red[j][col >> 6] = s;
    }
    __syncthreads();
    if (col < 8) rowsum[bc * 256 + row0 + col] = red[col][0] + red[col][1] + red[col][2] + red[col][3];
}

// ---------------- K3: kern2 from row sums (tiny MLP) ----------------
__global__ __launch_bounds__(256) void k_kern2(const float* __restrict__ rowsum,
                                               const float* __restrict__ w1, const float* __restrict__ b1,
                                               const float* __restrict__ w2, const float* __restrict__ b2,
                                               float* __restrict__ kern2) {
    __shared__ float ps[256];
    __shared__ float p2[64];
    __shared__ float h[64];
    int t = threadIdx.x;
    {
        int pair = t >> 2, seg = t & 3;
        const float* rs = rowsum + pair * 256 + seg * 64;
        float s = 0.f;
        for (int j = 0; j < 64; ++j) s += rs[j];
        ps[t] = s;
    }
    __syncthreads();
    if (t < 64) p2[t] = (ps[t * 4] + ps[t * 4 + 1] + ps[t * 4 + 2] + ps[t * 4 + 3]) * (1.f / 65536.f);
    __syncthreads();
    if (t < 64) {
        int b = t >> 4, j = t & 15;
        float a = b1[j];
        for (int i = 0; i < 16; ++i) a += p2[b * 16 + i] * w1[j * 16 + i];
        h[t] = fmaxf(a, 0.f);
    }
    __syncthreads();
    for (int i = t; i < 1600; i += 256) {     // 4 * 400
        int b = i / 400, o = i - b * 400;
        float a = b2[o];
        for (int j = 0; j < 16; ++j) a += h[b * 16 + j] * w2[o * 16 + j];
        kern2[i] = a;
    }
}

// ---------------- K4: dynamic depthwise 5x5 (8 rows/block, LDS-staged) ----------------
__global__ __launch_bounds__(256) void k_dw5(const float* __restrict__ y1,
                                             const float* __restrict__ kern2,
                                             float* __restrict__ x1o) {
    __shared__ float tile[12][260];
    int bid = blockIdx.x;            // bc*32 + rb
    int rb = bid & 31, bc = bid >> 5;
    int b = bc >> 4, c = bc & 15;
    int row0 = rb << 3;
    int col = threadIdx.x;
    const float* yc = y1 + ((size_t)bc << 16);
#pragma unroll
    for (int j = 0; j < 12; ++j) {
        int r = row0 - 2 + j;
        tile[j][col + 2] = ((unsigned)r < 256u) ? yc[(r << 8) + col] : 0.f;
    }
    if (col < 12) { tile[col][0] = 0.f; tile[col][1] = 0.f; tile[col][258] = 0.f; tile[col][259] = 0.f; }
    const float* k25 = kern2 + b * 400 + c * 25;
    float kk[25];
#pragma unroll
    for (int i = 0; i < 25; ++i) kk[i] = k25[i];
    __syncthreads();
#pragma unroll
    for (int j = 0; j < 8; ++j) {
        float acc = 0.f;
#pragma unroll
        for (int dy = 0; dy < 5; ++dy)
#pragma unroll
            for (int dx = 0; dx < 5; ++dx)
                acc += kk[dy * 5 + dx] * tile[j + dy][col + dx];
        x1o[((size_t)bc << 16) + ((row0 + j) << 8) + col] = acc;
    }
}

// ---------------- K5: fused fsas + final conv (exact R8 structure, best measured) ----------------
__global__ __launch_bounds__(512, 6) void k_fsas(const float* __restrict__ x,
                                                 const _Float16* __restrict__ hwH, const float* __restrict__ hid_b,
                                                 const float* __restrict__ dw_w, const float* __restrict__ dw_b,
                                                 const float* __restrict__ ln_w, const float* __restrict__ ln_b,
                                                 const _Float16* __restrict__ owlwH, const float* __restrict__ out_b,
                                                 const float* __restrict__ last_b,
                                                 const float* __restrict__ x1o, float* __restrict__ out) {
    __shared__ __align__(16) _Float16 Sbig[17856];
    __shared__ __align__(16) _Float16 qk[6144];
    __shared__ __align__(16) float pstat[128];

    _Float16* Abuf = Sbig;                     // [128][72]
    _Float16* hbuf = Sbig;                     // [144][124]
    _Float16* fbuf = Sbig;                     // [64][72]
    float*    lnp  = (float*)(Sbig + 4608);    // f32[1024]
    _Float16* outb = Sbig + 6656;              // [48][66]
    _Float16* qbuf = qk;                       // [48][64]
    _Float16* kbuf = qk + 3072;                // [48][64] krev
    _Float16* sbufA = qk;                      // [64][64] sswz overlay

    int tid = threadIdx.x;
    int lane = tid & 63;
    int wave = __builtin_amdgcn_readfirstlane(tid >> 6);
    int bid = blockIdx.x;
    int swz = ((bid & 7) << 9) | (bid >> 3);        // bijective XCD swizzle (4096 = 8*512)
    int b = swz >> 10;
    int rem = swz & 1023;
    int row0 = (rem >> 5) << 3, col0 = (rem & 31) << 3;

    int l16 = lane & 15, lhi = lane >> 4;
    int mb = wave * 16 + (lhi << 2);           // MFMA C-row base
    bool vok[4];
#pragma unroll
    for (int r = 0; r < 4; ++r) {
        int m = mb + r;
        int yv = m / 12, xv = m - yv * 12;
        vok[r] = (m < 120) && (xv < 10) &&
                 ((unsigned)(row0 - 1 + yv) < 256u) && ((unsigned)(col0 - 1 + xv) < 256u);
    }

    // ---- stage 1: fill A halo (p = y*12+x, k-pairs) + zero k-pad ----
    if (tid < 480) {
        int k2 = tid / 20, r20 = tid - (tid / 20) * 20;
        int y = r20 >> 1, xh = r20 & 1;
        int gy = row0 - 1 + y;
        bool rowok = (unsigned)gy < 256u;
        const float* xa = x + ((size_t)(b * 64 + 16 + 2 * k2) << 16) + ((size_t)(gy & 255) << 8);
        const float* xb = xa + 65536;
#pragma unroll
        for (int xx = 0; xx < 6; ++xx) {
            int xv = xh * 6 + xx;
            int gx = col0 - 1 + xv;
            bool ok = rowok && (xv < 10) && ((unsigned)gx < 256u);
            float va = ok ? xa[gx] : 0.f;
            float vb = ok ? xb[gx] : 0.f;
            *(h2*)(Abuf + (y * 12 + xv) * 72 + 2 * k2) = (h2){(_Float16)va, (_Float16)vb};
        }
    }
    if (tid < 240) {                    // k 48..63, rows 0..119
        int p = tid >> 1, kb = 48 + ((tid & 1) << 3);
        *(h8*)(Abuf + p * 72 + kb) = (h8)(_Float16)0.f;
    }
    __syncthreads();

    // a-frags (rows >=120 read garbage; outputs discarded by vok mask)
    int arow = wave * 16 + l16;
    h8 a0 = *(const h8*)(Abuf + arow * 72 + (lhi << 3));
    h8 a1 = *(const h8*)(Abuf + arow * 72 + 32 + (lhi << 3));
    __syncthreads();   // Abuf dead -> hbuf overlay safe

    // x1o early loads for waves 6-7 (consumed into fbuf at stage 4)
    float xr[8];
    int fpx = lane, fgrp = wave - 6;
    if (wave >= 6) {
        size_t gp = ((size_t)(row0 + (fpx >> 3)) << 8) + col0 + (fpx & 7);
#pragma unroll
        for (int j = 0; j < 8; ++j)
            xr[j] = x1o[((size_t)(b * 16 + fgrp * 8 + j) << 16) + gp];
    }

    // ---- stage 2: all 144 hidden channels, one MFMA burst (B from global, L2-hot) ----
#pragma unroll
    for (int nt = 0; nt < 9; ++nt) {
        const _Float16* wr = hwH + (nt * 16 + l16) * 72 + (lhi << 3);
        h8 b0 = *(const h8*)(wr);
        h8 b1 = *(const h8*)(wr + 32);
        float bias = hid_b[nt * 16 + l16];
        f4 acc = {bias, bias, bias, bias};
        acc = __builtin_amdgcn_mfma_f32_16x16x32_f16(a0, b0, acc, 0, 0, 0);
        acc = __builtin_amdgcn_mfma_f32_16x16x32_f16(a1, b1, acc, 0, 0, 0);
        int n_l = nt * 16 + l16;
        if (mb < 120) {
            h2 p0 = {vok[0] ? (_Float16)acc[0] : (_Float16)0.f, vok[1] ? (_Float16)acc[1] : (_Float16)0.f};
            h2 p1 = {vok[2] ? (_Float16)acc[2] : (_Float16)0.f, vok[3] ? (_Float16)acc[3] : (_Float16)0.f};
            *(h2*)(hbuf + n_l * 124 + mb) = p0;
            *(h2*)(hbuf + n_l * 124 + mb + 2) = p1;
        }
    }
    __syncthreads();

    // ---- stage 3: depthwise 3x3 via fdot2 (fp16 weights, f32 accum) ----
    int dch = tid >> 3, drow = tid & 7;
    h8 vreg;
    auto dw_row = [&](int ch, int row, float o[8]) {
        const float* dwp = dw_w + ch * 9;
        float bias = dw_b[ch];
#pragma unroll
        for (int xx = 0; xx < 8; ++xx) o[xx] = bias;
        const _Float16* hb = hbuf + ch * 124 + row * 12;
#pragma unroll
        for (int dy = 0; dy < 3; ++dy) {
            u32x2 A2 = *(const u32x2*)(hb + dy * 12);
            u32x2 B2 = *(const u32x2*)(hb + dy * 12 + 4);
            u32 r89 = *(const u32*)(hb + dy * 12 + 8);
            u32 r01 = A2.x, r23 = A2.y, r45 = B2.x, r67 = B2.y;
            u32 s12 = __builtin_amdgcn_alignbit(r23, r01, 16);
            u32 s34 = __builtin_amdgcn_alignbit(r45, r23, 16);
            u32 s56 = __builtin_amdgcn_alignbit(r67, r45, 16);
            u32 s78 = __builtin_amdgcn_alignbit(r89, r67, 16);
            _Float16 w0 = (_Float16)dwp[dy * 3], w1 = (_Float16)dwp[dy * 3 + 1], w2 = (_Float16)dwp[dy * 3 + 2];
            h2 w01 = {w0, w1};
            h2 w2lo = {w2, (_Float16)0.f};
            h2 w2hi = {(_Float16)0.f, w2};
            o[0] = __builtin_amdgcn_fdot2(w01, bch2(r01), o[0], false);
            o[0] = __builtin_amdgcn_fdot2(w2lo, bch2(r23), o[0], false);
            o[1] = __builtin_amdgcn_fdot2(w01, bch2(s12), o[1], false);
            o[1] = __builtin_amdgcn_fdot2(w2lo, bch2(s34), o[1], false);
            o[2] = __builtin_amdgcn_fdot2(w01, bch2(r23), o[2], false);
            o[2] = __builtin_amdgcn_fdot2(w2lo, bch2(r45), o[2], false);
            o[3] = __builtin_amdgcn_fdot2(w01, bch2(s34), o[3], false);
            o[3] = __builtin_amdgcn_fdot2(w2lo, bch2(s56), o[3], false);
            o[4] = __builtin_amdgcn_fdot2(w01, bch2(r45), o[4], false);
            o[4] = __builtin_amdgcn_fdot2(w2lo, bch2(r67), o[4], false);
            o[5] = __builtin_amdgcn_fdot2(w01, bch2(s56), o[5], false);
            o[5] = __builtin_amdgcn_fdot2(w2lo, bch2(s78), o[5], false);
            o[6] = __builtin_amdgcn_fdot2(w01, bch2(r67), o[6], false);
            o[6] = __builtin_amdgcn_fdot2(w2lo, bch2(r89), o[6], false);
            o[7] = __builtin_amdgcn_fdot2(w01, bch2(s78), o[7], false);
            o[7] = __builtin_amdgcn_fdot2(w2hi, bch2(r89), o[7], false);
        }
    };
    if (tid < 384) {
        float oq[8];
        dw_row(dch, drow, oq);                 // q
        h8 qv;
#pragma unroll
        for (int xx = 0; xx < 8; ++xx) qv[xx] = (_Float16)oq[xx];
        *(h8*)(qbuf + dch * 64 + drow * 8) = qv;
        float ov[8];
        dw_row(96 + dch, drow, ov);            // v -> regs
#pragma unroll
        for (int xx = 0; xx < 8; ++xx) vreg[xx] = (_Float16)ov[xx];
    } else {
        int j0 = (tid - 384) * 3;
#pragma unroll
        for (int i = 0; i < 3; ++i) {
            int j = j0 + i;
            int kc = j >> 3, kr = j & 7;
            float ok8[8];
            dw_row(48 + kc, kr, ok8);          // k
            h8 krv;
#pragma unroll
            for (int t2 = 0; t2 < 8; ++t2) krv[t2] = (_Float16)ok8[(8 - t2) & 7];
            *(h8*)(kbuf + kc * 64 + kr * 8) = krv;
        }
    }
    __syncthreads();

    // ---- stage 4: 8x8 circular conv via fdot2 (threads<384); fbuf x1 writes (waves 6-7) ----
    float co[8];
    if (tid < 384) {
        int ch = dch, m = drow;
#pragma unroll
        for (int n = 0; n < 8; ++n) co[n] = 0.f;
#pragma unroll
        for (int i8 = 0; i8 < 8; ++i8) {
            int r = (m - i8) & 7;
            u32x4 qv = *(const u32x4*)(qbuf + ch * 64 + i8 * 8);
            u32x4 ev = *(const u32x4*)(kbuf + ch * 64 + r * 8);
            h2 qp[4] = {bch2(qv.x), bch2(qv.y), bch2(qv.z), bch2(qv.w)};
            h2 ep[4] = {bch2(ev.x), bch2(ev.y), bch2(ev.z), bch2(ev.w)};
            h2 op[4] = {bch2(__builtin_amdgcn_alignbit(ev.x, ev.w, 16)),
                        bch2(__builtin_amdgcn_alignbit(ev.y, ev.x, 16)),
                        bch2(__builtin_amdgcn_alignbit(ev.z, ev.y, 16)),
                        bch2(__builtin_amdgcn_alignbit(ev.w, ev.z, 16))};
#pragma unroll
            for (int u = 0; u < 4; ++u)
#pragma unroll
                for (int a = 0; a < 4; ++a) {
                    co[2 * u]     = __builtin_amdgcn_fdot2(qp[a], ep[(a - u) & 3], co[2 * u], false);
                    co[2 * u + 1] = __builtin_amdgcn_fdot2(qp[a], op[(a - u) & 3], co[2 * u + 1], false);
                }
        }
#pragma unroll
        for (int v = 0; v < 4; ++v)
            *(h2*)(outb + dch * 66 + drow * 8 + 2 * v) = (h2){(_Float16)co[2 * v], (_Float16)co[2 * v + 1]};
    } else {
        h8 fv;
#pragma unroll
        for (int j = 0; j < 8; ++j) fv[j] = (_Float16)xr[j];
        *(h8*)(fbuf + fpx * 72 + fgrp * 8) = fv;
    }
    __syncthreads();

    // ---- stage 5a: layernorm stats ----
    {
        int px = tid & 63, g = tid >> 6;
        float s = 0.f, ss = 0.f;
#pragma unroll
        for (int cc = 0; cc < 6; ++cc) {
            float v = (float)outb[(g * 6 + cc) * 66 + px];
            s += v; ss += v * v;
        }
        lnp[g * 64 + px] = s;
        lnp[512 + g * 64 + px] = ss;
    }
    __syncthreads();
    if (tid < 64) {
        float s = 0.f, ss = 0.f;
#pragma unroll
        for (int g = 0; g < 8; ++g) { s += lnp[g * 64 + tid]; ss += lnp[512 + g * 64 + tid]; }
        float mu = s * (1.f / 48.f);
        float var = ss * (1.f / 48.f) - mu * mu;
        pstat[tid * 2] = mu;
        pstat[tid * 2 + 1] = rsqrtf(var + 1e-6f);
    }
    __syncthreads();

    // ---- stage 5b: sbufA[px][ch] = v * layernorm(out) (sswz); pad cols 48..63 ----
    if (tid < 384) {
        float lw = ln_w[dch], lb = ln_b[dch];
        const float* ps = pstat + drow * 16;
#pragma unroll
        for (int n = 0; n < 8; ++n) {
            float mu = ps[2 * n], inv = ps[2 * n + 1];
            float lnv = lw * ((co[n] - mu) * inv) + lb;
            sbufA[sswz(drow * 8 + n, dch)] = (_Float16)((float)vreg[n] * lnv);
        }
    }
    *(h2*)(sbufA + sswz(lane, 48 + (wave << 1))) = (h2){(_Float16)0.f, (_Float16)0.f};
    __syncthreads();

    // ---- stage 6: x2o = out_w @ sbuf + out_b -> fbuf[px][16+n] ----
    for (int t = wave; t < 12; t += 8) {
        int mt = t / 3, nt = t - mt * 3;
        int row5 = mt * 16 + l16;
        h8 c0 = *(const h8*)(sbufA + sswz(row5, lhi << 3));
        h8 c1 = *(const h8*)(sbufA + sswz(row5, 32 + (lhi << 3)));
        h8 d0 = *(const h8*)(owlwH + nt * 1152 + l16 * 72 + (lhi << 3));
        h8 d1 = *(const h8*)(owlwH + nt * 1152 + l16 * 72 + 32 + (lhi << 3));
        float bias = out_b[nt * 16 + l16];
        f4 acc = {bias, bias, bias, bias};
        acc = __builtin_amdgcn_mfma_f32_16x16x32_f16(c0, d0, acc, 0, 0, 0);
        acc = __builtin_amdgcn_mfma_f32_16x16x32_f16(c1, d1, acc, 0, 0, 0);
        int n5 = nt * 16 + l16;
        int pb = mt * 16 + (lhi << 2);
#pragma unroll
        for (int r = 0; r < 4; ++r)
            fbuf[(pb + r) * 72 + 16 + n5] = (_Float16)acc[r];
    }
    __syncthreads();

    // ---- stage 7: out = last_w @ [x1;x2o] + last_b -> direct global float4 ----
    for (int t = wave; t < 16; t += 8) {
        int mt = t >> 2, nt = t & 3;
        int row6 = mt * 16 + l16;
        h8 c0 = *(const h8*)(fbuf + row6 * 72 + (lhi << 3));
        h8 c1 = *(const h8*)(fbuf + row6 * 72 + 32 + (lhi << 3));
        h8 d0 = *(const h8*)(owlwH + 3456 + nt * 1152 + l16 * 72 + (lhi << 3));
        h8 d1 = *(const h8*)(owlwH + 3456 + nt * 1152 + l16 * 72 + 32 + (lhi << 3));
        float bias = last_b[nt * 16 + l16];
        f4 acc = {bias, bias, bias, bias};
        acc = __builtin_amdgcn_mfma_f32_16x16x32_f16(c0, d0, acc, 0, 0, 0);
        acc = __builtin_amdgcn_mfma_f32_16x16x32_f16(c1, d1, acc, 0, 0, 0);
        int ch = nt * 16 + l16;
        int px0 = mt * 16 + (lhi << 2);
        float4 val = {acc[0], acc[1], acc[2], acc[3]};
        *(float4*)(out + ((size_t)(b * 64 + ch) << 16) + ((size_t)(row0 + (px0 >> 3)) << 8) + col0 + (px0 & 7)) = val;
    }
}

extern "C" void kernel_launch(void* const* d_in, const int* in_sizes, int n_in,
                              void* d_out, int out_size, void* d_ws, size_t ws_size,
                              hipStream_t stream) {
    const float* x      = (const float*)d_in[0];
    const float* dl1_w1 = (const float*)d_in[1];
    const float* dl1_b1 = (const float*)d_in[2];
    const float* dl1_w2 = (const float*)d_in[3];
    const float* dl1_b2 = (const float*)d_in[4];
    const float* dl2_w1 = (const float*)d_in[5];
    const float* dl2_b1 = (const float*)d_in[6];
    const float* dl2_w2 = (const float*)d_in[7];
    const float* dl2_b2 = (const float*)d_in[8];
    const float* hid_w  = (const float*)d_in[9];
    const float* hid_b  = (const float*)d_in[10];
    const float* dw_w   = (const float*)d_in[11];
    const float* dw_b   = (const float*)d_in[12];
    const float* ln_w   = (const float*)d_in[13];
    const float* ln_b   = (const float*)d_in[14];
    const float* out_w  = (const float*)d_in[15];
    const float* out_b  = (const float*)d_in[16];
    const float* last_w = (const float*)d_in[17];
    const float* last_b = (const float*)d_in[18];
    float* out = (float*)d_out;

    float* ws      = (float*)d_ws;
    float* pooled1 = ws;                       // 64
    float* rowsum  = ws + 1024;                // 16384
    float* kern2   = ws + 17408;               // 1600
    _Float16* hwH   = (_Float16*)(ws + 19008); // 10368 fp16
    _Float16* owlwH = (_Float16*)(ws + 24192); // 8064 fp16 -> ends 28224
    float* y1      = ws + 32768;               // 4194304
    float* x1o     = ws + 32768 + 4194304;     // 4194304

    k_preppool <<<64,  256, 0, stream>>>(x, hid_w, out_w, last_w, hwH, owlwH, pooled1);
    k_dw3  <<<2048, 256, 0, stream>>>(x, pooled1, dl1_w1, dl1_b1, dl1_w2, dl1_b2, y1, rowsum);
    k_kern2<<<1,    256, 0, stream>>>(rowsum, dl2_w1, dl2_b1, dl2_w2, dl2_b2, kern2);
    k_dw5  <<<2048, 256, 0, stream>>>(y1, kern2, x1o);
    k_fsas <<<4096, 512, 0, stream>>>(x, hwH, hid_b, dw_w, dw_b, ln_w, ln_b,
                                      owlwH, out_b, last_b, x1o, out);
}